// Round 16
// baseline (29.425 us; speedup 1.0000x reference)
//
#include <hip/hip_runtime.h>

// Problem constants
#define NB 8
#define CH 64
#define KP 8            // K = C/8
#define HWP 4096        // H*W
#define NHW (NB * HWP)  // 32768
#define PTILE 32        // p-rows per attn block

typedef float f32x16 __attribute__((ext_vector_type(16)));
typedef __bf16 bf16x8 __attribute__((ext_vector_type(8)));
typedef short short8v __attribute__((ext_vector_type(8)));

// Workspace layout (float offsets)
#define WS_FB  0                 // f bf16 [NB][HWP][8], pre-scaled by log2(e)
#define WS_GB  (NHW * 4)         // g bf16 [NB][HWP][8]
#define WS_SB  (NHW * 8)         // s bf16 [NB][HWP], pre-shuffled per 16

// s shuffle: within each 16-block, position j holds s[porder[j]],
// porder = {0,1,2,3, 8,9,10,11, 4,5,6,7, 12,13,14,15} (involution).
// Makes PV MFMA A-frag k-order match the e-tile C-reg q-order (verified R6-R15).
__device__ __forceinline__ int s_shuf_idx(int i) {
    return i ^ (((((i >> 2) ^ (i >> 3)) & 1) != 0) ? 12 : 0);
}

// ---------------------------------------------------------------------------
// Kernel 1: 1x1-conv projections. R16: 8-way channel split (512 blocks x
// 512 thr = 4096 waves = 4 waves/SIMD, 2x R12). Each thread: 8 coalesced
// x loads (one 8-channel slice of 64 px), 17 partial accumulators; slices
// 1-7 park partials in LDS (stride 17, conflict-free); slice 0 reduces and
// emits the exact verified outputs (bf16 f*L2E, bf16 g, shuffled bf16 s).
// ---------------------------------------------------------------------------
__global__ __launch_bounds__(512) void proj_kernel(
    const float* __restrict__ x,
    const float* __restrict__ Wf, const float* __restrict__ bf,
    const float* __restrict__ Wg, const float* __restrict__ bg,
    const float* __restrict__ Ws, const float* __restrict__ bs,
    float* __restrict__ ws)
{
    __shared__ float part[7][64][17];     // 30.3 KB

    const int blk = blockIdx.x;           // 512 blocks: 64 per batch
    const int n   = blk >> 6;
    const int p0  = (blk & 63) << 6;      // 64 pixels per block
    const int px  = threadIdx.x & 63;
    const int q   = threadIdx.x >> 6;     // c-slice 0..7 (wave-uniform)
    const int p   = p0 + px;

    const float* xp = x + (size_t)n * CH * HWP + (size_t)(q * 8) * HWP + p;

    float accf[KP], accg[KP], accs;
    if (q == 0) {
#pragma unroll
        for (int k = 0; k < KP; ++k) { accf[k] = bf[k]; accg[k] = bg[k]; }
        accs = bs[0];
    } else {
#pragma unroll
        for (int k = 0; k < KP; ++k) { accf[k] = 0.f; accg[k] = 0.f; }
        accs = 0.f;
    }

#pragma unroll
    for (int c = 0; c < 8; ++c) {         // 8 independent coalesced loads
        float xv = xp[(size_t)c * HWP];
        int cc = q * 8 + c;
#pragma unroll
        for (int k = 0; k < KP; ++k) {
            accf[k] = fmaf(Wf[k * CH + cc], xv, accf[k]);
            accg[k] = fmaf(Wg[k * CH + cc], xv, accg[k]);
        }
        accs = fmaf(Ws[cc], xv, accs);
    }

    if (q != 0) {
        float* dst = part[q - 1][px];
#pragma unroll
        for (int k = 0; k < KP; ++k) { dst[k] = accf[k]; dst[KP + k] = accg[k]; }
        dst[16] = accs;
    }
    __syncthreads();

    if (q == 0) {
#pragma unroll
        for (int j = 0; j < 7; ++j) {
            const float* src = part[j][px];
#pragma unroll
            for (int k = 0; k < KP; ++k) { accf[k] += src[k]; accg[k] += src[KP + k]; }
            accs += src[16];
        }

        const float L2E = 1.4426950408889634f;
        bf16x8 fv, gv;
#pragma unroll
        for (int k = 0; k < KP; ++k) {
            fv[k] = (__bf16)(accf[k] * L2E);
            gv[k] = (__bf16)accg[k];
        }

        ushort* fb = (ushort*)(ws + WS_FB) + (size_t)(n * HWP + p) * 8;
        ushort* gb = (ushort*)(ws + WS_GB) + (size_t)(n * HWP + p) * 8;
        *(short8v*)fb = __builtin_bit_cast(short8v, fv);
        *(short8v*)gb = __builtin_bit_cast(short8v, gv);

        __bf16 sb16 = (__bf16)accs;
        ((ushort*)(ws + WS_SB))[(size_t)n * HWP + (p & ~15) + s_shuf_idx(p & 15)] =
            __builtin_bit_cast(ushort, sb16);
    }
}

// ---------------------------------------------------------------------------
// Kernel 2 (fused attn + merge + epilogue). R15 structure (PTILE=32, 1024
// blocks, 8 q-split waves, barrier-free sweep, g direct from L2). R16: the
// epilogue's x float4 is prefetched right after the sweep so its latency
// hides under the merge barriers (T14). Tile math byte-identical R6-R15.
// ---------------------------------------------------------------------------
__global__ __launch_bounds__(512, 8) void attn_finish_kernel(
    const float* __restrict__ x, const float* __restrict__ gamma,
    float* __restrict__ ws, float* __restrict__ out)
{
    __shared__ alignas(16) ushort s_lds[HWP];   // 8 KB: whole shuffled s row
    __shared__ ushort ones_lds[32];             // 64 B
    __shared__ float  part_l[8][PTILE];         // 1 KB
    __shared__ float  part_a[8][PTILE];         // 1 KB
    __shared__ float  att_lds[PTILE];           // 128 B

    const int blk  = blockIdx.x;       // 1024 = n(8) * ptile(128)
    const int n    = blk >> 7;
    const int p0   = (blk & 127) << 5;
    const int tid  = threadIdx.x;
    const int lane = tid & 63;
    const int w    = tid >> 6;         // 0..7 = q-split (512 q each)
    const int l31  = lane & 31;
    const int hi   = lane >> 5;

    // stage whole s row (4096 bf16 = 512 float4s = 1/thread) + ones
    ((float4*)s_lds)[tid] =
        ((const float4*)((const ushort*)(ws + WS_SB) + (size_t)n * HWP))[tid];
    if (tid < 16) ((uint*)ones_lds)[tid] = 0x3F803F80u;

    // B-fragment: f rows for this block's 32 p (lanes 0-31 real)
    const ushort* fbase = (const ushort*)(ws + WS_FB) + (size_t)n * HWP * KP;
    short8v z8 = {0, 0, 0, 0, 0, 0, 0, 0};
    bf16x8 bfrag = __builtin_bit_cast(bf16x8,
        hi ? z8 : *(const short8v*)(fbase + (size_t)(p0 + l31) * KP));

    const ushort* gbase = (const ushort*)(ws + WS_GB) + (size_t)n * HWP * KP;

    __syncthreads();    // s_lds ready — last barrier until merge

    const f32x16 czero = {0.f};
    f32x16 c_pv = {0.f};

    const int qw = w << 9;             // wave's q range start (512 q)
    // prefetch tile 0's g row (lanes 0-31; hi lanes use zero frag)
    short8v araw = z8;
    if (!hi) araw = *(const short8v*)(gbase + (size_t)(qw + l31) * KP);

#pragma unroll 1
    for (int t = 0; t < 16; ++t) {     // 16 tiles of 32 q
        bf16x8 afrag = __builtin_bit_cast(bf16x8, araw);
        // prefetch next tile's g row (L2-hit, hides under exp2/cvt)
        if (t + 1 < 16 && !hi)
            araw = *(const short8v*)(gbase + (size_t)(qw + (t + 1) * 32 + l31) * KP);

        f32x16 c = __builtin_amdgcn_mfma_f32_32x32x16_bf16(
            afrag, bfrag, czero, 0, 0, 0);
#pragma unroll
        for (int r = 0; r < 16; ++r) c[r] = __builtin_amdgcn_exp2f(c[r]);

        bf16x8 elo, ehi;
#pragma unroll
        for (int r = 0; r < 8; ++r) { elo[r] = (__bf16)c[r]; ehi[r] = (__bf16)c[r + 8]; }

        const int qbase = qw + (t << 5);
        const ushort* ap = (l31 == 1) ? ones_lds : (s_lds + qbase + (hi << 3));
        bf16x8 a1 = __builtin_bit_cast(bf16x8, *(const short8v*)ap);
        bf16x8 a2 = __builtin_bit_cast(bf16x8, *(const short8v*)(ap + 16));

        c_pv = __builtin_amdgcn_mfma_f32_32x32x16_bf16(a1, elo, c_pv, 0, 0, 0);
        c_pv = __builtin_amdgcn_mfma_f32_32x32x16_bf16(a2, ehi, c_pv, 0, 0, 0);
    }

    // T14: prefetch the epilogue's x float4 NOW — latency hides under the
    // merge barriers instead of serializing in the epilogue.
    const int ec  = tid >> 3;          // 512 float4s over (c, p/4), 1/thread
    const int ep4 = (tid & 7) << 2;
    const float* xn = x + (size_t)n * CH * HWP + p0;
    float4 xv = *(const float4*)(xn + (size_t)ec * HWP + ep4);

    // partials: D rows 0 = sum e*s, 1 = sum e (regs 0,1 of hi=0 lanes)
    if (!hi) {
        part_a[w][l31] = c_pv[0];
        part_l[w][l31] = c_pv[1];
    }
    __syncthreads();

    // merge + att_map output
    if (tid < PTILE) {
        float l = 0.f, a = 0.f;
#pragma unroll
        for (int j = 0; j < 8; ++j) { l += part_l[j][tid]; a += part_a[j][tid]; }
        float att = a / l;
        att_lds[tid] = att;
        out[(size_t)n * HWP + p0 + tid] = att;
    }
    __syncthreads();

    // epilogue: out = att*gamma + x (x already in registers)
    const float gm = gamma[0];
    float* outp = out + NHW + (size_t)n * CH * HWP + p0;
    {
        float4 av = *(const float4*)(att_lds + ep4);
        float4 o;
        o.x = fmaf(av.x, gm, xv.x);
        o.y = fmaf(av.y, gm, xv.y);
        o.z = fmaf(av.z, gm, xv.z);
        o.w = fmaf(av.w, gm, xv.w);
        *(float4*)(outp + (size_t)ec * HWP + ep4) = o;
    }
}

extern "C" void kernel_launch(void* const* d_in, const int* in_sizes, int n_in,
                              void* d_out, int out_size, void* d_ws, size_t ws_size,
                              hipStream_t stream) {
    const float* x     = (const float*)d_in[0];
    const float* Wf    = (const float*)d_in[1];
    const float* bf    = (const float*)d_in[2];
    const float* Wg    = (const float*)d_in[3];
    const float* bg    = (const float*)d_in[4];
    const float* Ws    = (const float*)d_in[5];
    const float* bs    = (const float*)d_in[6];
    const float* gamma = (const float*)d_in[7];
    float* out = (float*)d_out;
    float* ws  = (float*)d_ws;

    // d_out layout: att_map [NB*HWP] then output [NB*CH*HWP]
    proj_kernel<<<NB * (HWP / 64), 512, 0, stream>>>(x, Wf, bf, Wg, bg, Ws, bs, ws);
    attn_finish_kernel<<<NB * (HWP / PTILE), 512, 0, stream>>>(x, gamma, ws, out);
}